// Round 3
// baseline (690.137 us; speedup 1.0000x reference)
//
#include <hip/hip_runtime.h>

#define B_ROWS 16384
#define K_DIM  128
#define C_CLS  32

// ws layout (bytes)
#define O_COUNTS   0
#define O_FIRST    256
#define O_RANK     512
#define O_OFFS     768
#define O_KLACC    1024
#define O_LD2      1152
#define O_COUNTSF  1280
#define O_COLSUM   2048            // 32*128*4 = 16384
#define O_MU       18432           // 16384
#define O_LIST     34816           // 16384*4 = 65536
#define O_S        102400          // 32*16384*4 = 2 MiB
#define O_INV      (102400 + 2097152)

// ---------------------------------------------------------------------------
// K1: counts, first-occurrence, appearance rank, offsets, class bucket list.
// Single block so no grid sync needed. 1024 threads, 16 rows each.
// ---------------------------------------------------------------------------
__global__ __launch_bounds__(1024) void k_bucket(const int* __restrict__ label,
    int* __restrict__ counts, int* __restrict__ rank_g, int* __restrict__ offs,
    float* __restrict__ countsf, int* __restrict__ list) {
  __shared__ int lc[C_CLS], lf[C_CLS], loff[C_CLS], lcur[C_CLS];
  const int t = threadIdx.x;
  if (t < C_CLS) { lc[t] = 0; lf[t] = 0x7fffffff; lcur[t] = 0; }
  __syncthreads();
  #pragma unroll
  for (int q = 0; q < 16; ++q) {
    int i = q * 1024 + t;
    int c = label[i];
    atomicAdd(&lc[c], 1);
    atomicMin(&lf[c], i);
  }
  __syncthreads();
  if (t == 0) {
    int run = 0;
    for (int c = 0; c < C_CLS; ++c) { loff[c] = run; run += lc[c]; }
  }
  __syncthreads();
  if (t < C_CLS) {
    counts[t]  = lc[t];
    countsf[t] = (float)lc[t];
    offs[t]    = loff[t];
    // rank = stable double-argsort of first-occurrence
    int f = lf[t], r = 0;
    for (int c2 = 0; c2 < C_CLS; ++c2) {
      int f2 = lf[c2];
      r += (f2 < f) || (f2 == f && c2 < t);
    }
    rank_g[t] = r;
  }
  #pragma unroll
  for (int q = 0; q < 16; ++q) {
    int i = q * 1024 + t;
    int c = label[i];
    int pos = atomicAdd(&lcur[c], 1);
    list[loff[c] + pos] = i;
  }
}

// ---------------------------------------------------------------------------
// K2: per-class second moment M_c = sum_{i in c} x_i x_i^T (atomic merge into S
// buffer) + per-class column sums. 4 splits per class -> 128 blocks.
// Each thread owns an 8x8 register tile of the 128x128 output.
// ---------------------------------------------------------------------------
__global__ __launch_bounds__(256) void k_scatter(const float* __restrict__ feat,
    const int* __restrict__ counts, const int* __restrict__ offs,
    const int* __restrict__ list, float* __restrict__ M, float* __restrict__ colsum) {
  const int c = blockIdx.x >> 2, s = blockIdx.x & 3;
  const int n = counts[c], off = offs[c];
  const int beg = off + (n * s) / 4, end = off + (n * (s + 1)) / 4;
  __shared__ __align__(16) float ls[32 * 128];
  const int t = threadIdx.x;
  const int tr = t >> 4, tc = t & 15;
  float acc[8][8];
  #pragma unroll
  for (int i = 0; i < 8; ++i)
    #pragma unroll
    for (int j = 0; j < 8; ++j) acc[i][j] = 0.f;
  float cs = 0.f;
  const int col = t & 127, half = t >> 7;
  for (int base = beg; base < end; base += 32) {
    const int nb = min(32, end - base);
    __syncthreads();             // protect ls against previous-iter readers
    #pragma unroll
    for (int w = 0; w < 4; ++w) {
      int f4 = w * 256 + t;      // 0..1023 over 32 rows x 32 float4
      int r = f4 >> 5, c4 = f4 & 31;
      float4 v = make_float4(0.f, 0.f, 0.f, 0.f);
      if (r < nb) {
        int row = list[base + r];
        v = ((const float4*)(feat + (long)row * K_DIM))[c4];
      }
      ((float4*)ls)[f4] = v;     // zero-padded tail rows contribute nothing
    }
    __syncthreads();
    #pragma unroll
    for (int r0 = 0; r0 < 16; ++r0) cs += ls[(half * 16 + r0) * 128 + col];
    for (int r = 0; r < nb; ++r) {
      const float4* lr = (const float4*)(ls + r * 128);
      float4 A0 = lr[tr * 2], A1 = lr[tr * 2 + 1];
      float4 B0 = lr[tc * 2], B1 = lr[tc * 2 + 1];
      float av[8] = {A0.x, A0.y, A0.z, A0.w, A1.x, A1.y, A1.z, A1.w};
      float bv[8] = {B0.x, B0.y, B0.z, B0.w, B1.x, B1.y, B1.z, B1.w};
      #pragma unroll
      for (int i = 0; i < 8; ++i)
        #pragma unroll
        for (int j = 0; j < 8; ++j) acc[i][j] += av[i] * bv[j];
    }
  }
  float* Mc = M + c * 16384;
  #pragma unroll
  for (int i = 0; i < 8; ++i)
    #pragma unroll
    for (int j = 0; j < 8; ++j)
      atomicAdd(&Mc[(tr * 8 + i) * 128 + (tc * 8 + j)], acc[i][j]);
  atomicAdd(&colsum[c * 128 + col], cs);
}

// ---------------------------------------------------------------------------
// K3: mu = colsum/n ; S = M/n - mu mu^T + I (in place over the M buffer)
// ---------------------------------------------------------------------------
__global__ __launch_bounds__(256) void k_finalize(float* __restrict__ S,
    const float* __restrict__ colsum, const float* __restrict__ countsf,
    float* __restrict__ mu) {
  const int c = blockIdx.x, t = threadIdx.x;
  __shared__ __align__(16) float ml[128];
  const float n = countsf[c];
  if (t < 128) {
    float m = colsum[c * 128 + t] / n;
    ml[t] = m;
    mu[c * 128 + t] = m;
  }
  __syncthreads();
  float4* S4 = (float4*)(S + c * 16384);
  const float rn = 1.0f / n;
  #pragma unroll
  for (int q = 0; q < 16; ++q) {
    int f4 = q * 256 + t;
    int a = f4 >> 5, b = (f4 & 31) * 4;
    float4 v = S4[f4];
    float ma = ml[a];
    v.x = v.x * rn - ma * ml[b + 0] + ((a == b + 0) ? 1.f : 0.f);
    v.y = v.y * rn - ma * ml[b + 1] + ((a == b + 1) ? 1.f : 0.f);
    v.z = v.z * rn - ma * ml[b + 2] + ((a == b + 2) ? 1.f : 0.f);
    v.w = v.w * rn - ma * ml[b + 3] + ((a == b + 3) ? 1.f : 0.f);
    S4[f4] = v;
  }
}

// ---------------------------------------------------------------------------
// K4: symmetric sweep-operator inversion + log2-det, register-resident.
// 512 threads/block: thread t holds 8 float4 = 32 elems -> rows rq = 16q + h
// (h = t>>5, q = 0..7), cols [4*(t&31) .. +3]. Spill fix vs r2: per-thread
// state halved (was 64 floats @256thr -> VGPR cap hit, 95 MB scratch traffic).
// Sweep preserves symmetry, so the pivot COLUMN values are read from the
// broadcast pivot ROW (vr = vbuf[rq]). det = prod pivots (>=1 since S >= I).
// One 512 B LDS row broadcast + 1 barrier per step; double-buffered vbuf
// avoids a second barrier; p-loop unrolled via template recursion so every
// register index is compile-time static.
// ---------------------------------------------------------------------------
template<int P>
__device__ __forceinline__ void sweep_step(float4 (&A)[8], float (*vbuf)[128],
                                           int h, int c4i, float& lda) {
  constexpr int buf = P & 1;
  if (h == (P & 15)) ((float4*)vbuf[buf])[c4i] = A[P >> 4];   // export row P
  __syncthreads();
  const float d = vbuf[buf][P];
  lda += __log2f(d);
  const float dinv = 1.0f / d;
  float4 vc = ((const float4*)vbuf[buf])[c4i];
  float4 wc = make_float4(vc.x * dinv, vc.y * dinv, vc.z * dinv, vc.w * dinv);
  const bool colp = (c4i == (P >> 2));
  #pragma unroll
  for (int q = 0; q < 8; ++q) {
    const int rq = q * 16 + h;
    const float vr = vbuf[buf][rq];
    float4 nA;
    nA.x = A[q].x - vr * wc.x;
    nA.y = A[q].y - vr * wc.y;
    nA.z = A[q].z - vr * wc.z;
    nA.w = A[q].w - vr * wc.w;
    if (q == (P >> 4)) {             // compile-time q selection
      if (h == (P & 15)) nA = wc;    // row P: B[P][c] = v[c]/d
    }
    if (colp) {                      // col P: B[r][P] = v[r]/d ; diag: -1/d
      float cp = (rq == P) ? -dinv : vr * dinv;
      if constexpr ((P & 3) == 0)      nA.x = cp;
      else if constexpr ((P & 3) == 1) nA.y = cp;
      else if constexpr ((P & 3) == 2) nA.z = cp;
      else                             nA.w = cp;
    }
    A[q] = nA;
  }
}

template<int P>
struct SweepUnroll {
  __device__ static __forceinline__ void run(float4 (&A)[8], float (*vbuf)[128],
                                             int h, int c4i, float& lda) {
    sweep_step<P>(A, vbuf, h, c4i, lda);
    SweepUnroll<P + 1>::run(A, vbuf, h, c4i, lda);
  }
};
template<>
struct SweepUnroll<128> {
  __device__ static __forceinline__ void run(float4 (&)[8], float (*)[128],
                                             int, int, float&) {}
};

__global__ __launch_bounds__(512) void k_sweep(const float* __restrict__ S,
    float* __restrict__ INVg, float* __restrict__ ld2) {
  const int c = blockIdx.x, t = threadIdx.x;
  __shared__ __align__(16) float vbuf[2][128];
  const float4* S4 = (const float4*)(S + c * 16384);
  float4 A[8];
  #pragma unroll
  for (int q = 0; q < 8; ++q) A[q] = S4[q * 512 + t];
  float lda = 0.f;
  const int h = t >> 5, c4i = t & 31;
  SweepUnroll<0>::run(A, vbuf, h, c4i, lda);
  float4* O4 = (float4*)(INVg + c * 16384);
  #pragma unroll
  for (int q = 0; q < 8; ++q)
    O4[q * 512 + t] = make_float4(-A[q].x, -A[q].y, -A[q].z, -A[q].w);
  if (t == 0) ld2[c] = lda;          // v_log_f32 is log2 -> matches slogdet/ln2
}

// ---------------------------------------------------------------------------
// K5: pairwise tr+quad fused: sum_f inv_j[f] * (S_i[f] + diff[a]*diff[b]);
// kl = 0.5*(ld2[j]-ld2[i] - 128 + sum); masked atomic accumulate.
// ---------------------------------------------------------------------------
__global__ __launch_bounds__(256) void k_pairs(const float* __restrict__ S,
    const float* __restrict__ INVg, const float* __restrict__ mu,
    const float* __restrict__ ld2, const int* __restrict__ rank_g,
    float* __restrict__ klacc) {
  const int j = blockIdx.x, i = blockIdx.y;
  if (rank_g[i] > C_CLS - 2 || rank_g[j] < 1) return;
  __shared__ __align__(16) float dl[128];
  __shared__ float wsum[4];
  const int t = threadIdx.x;
  if (t < 128) dl[t] = mu[i * 128 + t] - mu[j * 128 + t];
  __syncthreads();
  const float4* Si4 = (const float4*)(S + i * 16384);
  const float4* Ij4 = (const float4*)(INVg + j * 16384);
  float s = 0.f;
  #pragma unroll
  for (int q = 0; q < 16; ++q) {
    int f4 = q * 256 + t;
    int a = f4 >> 5, b4 = f4 & 31;
    float da = dl[a];
    float4 db = ((const float4*)dl)[b4];
    float4 si = Si4[f4], ij = Ij4[f4];
    s += ij.x * (si.x + da * db.x);
    s += ij.y * (si.y + da * db.y);
    s += ij.z * (si.z + da * db.z);
    s += ij.w * (si.w + da * db.w);
  }
  #pragma unroll
  for (int off = 32; off > 0; off >>= 1) s += __shfl_xor(s, off);
  if ((t & 63) == 0) wsum[t >> 6] = s;
  __syncthreads();
  if (t == 0) {
    float tot = wsum[0] + wsum[1] + wsum[2] + wsum[3];
    float kl = 0.5f * ((ld2[j] - ld2[i]) - 128.0f + tot);
    atomicAdd(klacc, kl);
  }
}

// ---------------------------------------------------------------------------
// K6: out = klacc - sum(mu^2)
// ---------------------------------------------------------------------------
__global__ __launch_bounds__(256) void k_final(const float* __restrict__ mu,
    const float* __restrict__ klacc, float* __restrict__ out) {
  const int t = threadIdx.x;
  __shared__ float wsum[4];
  float s = 0.f;
  #pragma unroll
  for (int q = 0; q < 16; ++q) {
    float m = mu[q * 256 + t];
    s += m * m;
  }
  #pragma unroll
  for (int off = 32; off > 0; off >>= 1) s += __shfl_xor(s, off);
  if ((t & 63) == 0) wsum[t >> 6] = s;
  __syncthreads();
  if (t == 0) out[0] = klacc[0] - (wsum[0] + wsum[1] + wsum[2] + wsum[3]);
}

extern "C" void kernel_launch(void* const* d_in, const int* in_sizes, int n_in,
                              void* d_out, int out_size, void* d_ws, size_t ws_size,
                              hipStream_t stream) {
  const float* feat  = (const float*)d_in[0];
  const int*   label = (const int*)d_in[1];
  // d_in[2] (pan) is unused by the reference module.
  float* out = (float*)d_out;
  char*  ws  = (char*)d_ws;

  int*   counts  = (int*)(ws + O_COUNTS);
  int*   rank_g  = (int*)(ws + O_RANK);
  int*   offs    = (int*)(ws + O_OFFS);
  float* klacc   = (float*)(ws + O_KLACC);
  float* ld2     = (float*)(ws + O_LD2);
  float* countsf = (float*)(ws + O_COUNTSF);
  float* colsum  = (float*)(ws + O_COLSUM);
  float* mu      = (float*)(ws + O_MU);
  int*   list    = (int*)(ws + O_LIST);
  float* S       = (float*)(ws + O_S);
  float* INVg    = (float*)(ws + O_INV);

  hipMemsetAsync(ws, 0, 18432, stream);                 // header + colsum
  hipMemsetAsync(S, 0, C_CLS * 16384 * 4, stream);      // M accumulators

  k_bucket  <<<1,            1024, 0, stream>>>(label, counts, rank_g, offs, countsf, list);
  k_scatter <<<128,           256, 0, stream>>>(feat, counts, offs, list, S, colsum);
  k_finalize<<<C_CLS,         256, 0, stream>>>(S, colsum, countsf, mu);
  k_sweep   <<<C_CLS,         512, 0, stream>>>(S, INVg, ld2);
  k_pairs   <<<dim3(C_CLS, C_CLS), 256, 0, stream>>>(S, INVg, mu, ld2, rank_g, klacc);
  k_final   <<<1,             256, 0, stream>>>(mu, klacc, out);
}

// Round 4
// 228.480 us; speedup vs baseline: 3.0206x; 3.0206x over previous
//
#include <hip/hip_runtime.h>

#define B_ROWS 16384
#define K_DIM  128
#define C_CLS  32

// ws layout (bytes)
#define O_COUNTS   0
#define O_FIRST    256
#define O_RANK     512
#define O_OFFS     768
#define O_KLACC    1024
#define O_LD2      1152
#define O_COUNTSF  1280
#define O_COLSUM   2048            // 32*128*4 = 16384
#define O_MU       18432           // 16384
#define O_LIST     34816           // 16384*4 = 65536
#define O_S        102400          // 32*16384*4 = 2 MiB
#define O_INV      (102400 + 2097152)

// ---------------------------------------------------------------------------
// K1: counts, first-occurrence, appearance rank, offsets, class bucket list.
// Single block so no grid sync needed. 1024 threads, 16 rows each.
// ---------------------------------------------------------------------------
__global__ __launch_bounds__(1024) void k_bucket(const int* __restrict__ label,
    int* __restrict__ counts, int* __restrict__ rank_g, int* __restrict__ offs,
    float* __restrict__ countsf, int* __restrict__ list) {
  __shared__ int lc[C_CLS], lf[C_CLS], loff[C_CLS], lcur[C_CLS];
  const int t = threadIdx.x;
  if (t < C_CLS) { lc[t] = 0; lf[t] = 0x7fffffff; lcur[t] = 0; }
  __syncthreads();
  #pragma unroll
  for (int q = 0; q < 16; ++q) {
    int i = q * 1024 + t;
    int c = label[i];
    atomicAdd(&lc[c], 1);
    atomicMin(&lf[c], i);
  }
  __syncthreads();
  if (t == 0) {
    int run = 0;
    for (int c = 0; c < C_CLS; ++c) { loff[c] = run; run += lc[c]; }
  }
  __syncthreads();
  if (t < C_CLS) {
    counts[t]  = lc[t];
    countsf[t] = (float)lc[t];
    offs[t]    = loff[t];
    // rank = stable double-argsort of first-occurrence
    int f = lf[t], r = 0;
    for (int c2 = 0; c2 < C_CLS; ++c2) {
      int f2 = lf[c2];
      r += (f2 < f) || (f2 == f && c2 < t);
    }
    rank_g[t] = r;
  }
  #pragma unroll
  for (int q = 0; q < 16; ++q) {
    int i = q * 1024 + t;
    int c = label[i];
    int pos = atomicAdd(&lcur[c], 1);
    list[loff[c] + pos] = i;
  }
}

// ---------------------------------------------------------------------------
// K2: per-class second moment M_c = sum_{i in c} x_i x_i^T (atomic merge into S
// buffer) + per-class column sums. 4 splits per class -> 128 blocks.
// Each thread owns an 8x8 register tile of the 128x128 output.
// ---------------------------------------------------------------------------
__global__ __launch_bounds__(256) void k_scatter(const float* __restrict__ feat,
    const int* __restrict__ counts, const int* __restrict__ offs,
    const int* __restrict__ list, float* __restrict__ M, float* __restrict__ colsum) {
  const int c = blockIdx.x >> 2, s = blockIdx.x & 3;
  const int n = counts[c], off = offs[c];
  const int beg = off + (n * s) / 4, end = off + (n * (s + 1)) / 4;
  __shared__ __align__(16) float ls[32 * 128];
  const int t = threadIdx.x;
  const int tr = t >> 4, tc = t & 15;
  float acc[8][8];
  #pragma unroll
  for (int i = 0; i < 8; ++i)
    #pragma unroll
    for (int j = 0; j < 8; ++j) acc[i][j] = 0.f;
  float cs = 0.f;
  const int col = t & 127, half = t >> 7;
  for (int base = beg; base < end; base += 32) {
    const int nb = min(32, end - base);
    __syncthreads();             // protect ls against previous-iter readers
    #pragma unroll
    for (int w = 0; w < 4; ++w) {
      int f4 = w * 256 + t;      // 0..1023 over 32 rows x 32 float4
      int r = f4 >> 5, c4 = f4 & 31;
      float4 v = make_float4(0.f, 0.f, 0.f, 0.f);
      if (r < nb) {
        int row = list[base + r];
        v = ((const float4*)(feat + (long)row * K_DIM))[c4];
      }
      ((float4*)ls)[f4] = v;     // zero-padded tail rows contribute nothing
    }
    __syncthreads();
    #pragma unroll
    for (int r0 = 0; r0 < 16; ++r0) cs += ls[(half * 16 + r0) * 128 + col];
    for (int r = 0; r < nb; ++r) {
      const float4* lr = (const float4*)(ls + r * 128);
      float4 A0 = lr[tr * 2], A1 = lr[tr * 2 + 1];
      float4 B0 = lr[tc * 2], B1 = lr[tc * 2 + 1];
      float av[8] = {A0.x, A0.y, A0.z, A0.w, A1.x, A1.y, A1.z, A1.w};
      float bv[8] = {B0.x, B0.y, B0.z, B0.w, B1.x, B1.y, B1.z, B1.w};
      #pragma unroll
      for (int i = 0; i < 8; ++i)
        #pragma unroll
        for (int j = 0; j < 8; ++j) acc[i][j] += av[i] * bv[j];
    }
  }
  float* Mc = M + c * 16384;
  #pragma unroll
  for (int i = 0; i < 8; ++i)
    #pragma unroll
    for (int j = 0; j < 8; ++j)
      atomicAdd(&Mc[(tr * 8 + i) * 128 + (tc * 8 + j)], acc[i][j]);
  atomicAdd(&colsum[c * 128 + col], cs);
}

// ---------------------------------------------------------------------------
// K3: mu = colsum/n ; S = M/n - mu mu^T + I (in place over the M buffer)
// ---------------------------------------------------------------------------
__global__ __launch_bounds__(256) void k_finalize(float* __restrict__ S,
    const float* __restrict__ colsum, const float* __restrict__ countsf,
    float* __restrict__ mu) {
  const int c = blockIdx.x, t = threadIdx.x;
  __shared__ __align__(16) float ml[128];
  const float n = countsf[c];
  if (t < 128) {
    float m = colsum[c * 128 + t] / n;
    ml[t] = m;
    mu[c * 128 + t] = m;
  }
  __syncthreads();
  float4* S4 = (float4*)(S + c * 16384);
  const float rn = 1.0f / n;
  #pragma unroll
  for (int q = 0; q < 16; ++q) {
    int f4 = q * 256 + t;
    int a = f4 >> 5, b = (f4 & 31) * 4;
    float4 v = S4[f4];
    float ma = ml[a];
    v.x = v.x * rn - ma * ml[b + 0] + ((a == b + 0) ? 1.f : 0.f);
    v.y = v.y * rn - ma * ml[b + 1] + ((a == b + 1) ? 1.f : 0.f);
    v.z = v.z * rn - ma * ml[b + 2] + ((a == b + 2) ? 1.f : 0.f);
    v.w = v.w * rn - ma * ml[b + 3] + ((a == b + 3) ? 1.f : 0.f);
    S4[f4] = v;
  }
}

// ---------------------------------------------------------------------------
// K4: sweep-operator inversion + log2-det. ROLLED loop (spill fix vs r2/r3:
// the 128-deep template unroll made A[]'s live ranges span 128 barriers ->
// LLVM greedy RA spilled ~11.6 KB/thread to scratch at ANY thread-state size;
// a rolled loop keeps the region small, all A[] indices remain static).
//
// Layout: 512 threads; thread t holds rows rq = 16q + h (h = t>>5, q=0..7),
// float4-cols [4*(t&31) .. +3] -> A[8] = 32 VGPRs of data.
//
// In-LDS pivot fixup removes ALL per-element predication from the hot loop:
// exporter writes row P with vbuf[P] := d-1 (and raw d into slot 128). Then
// the generic update A -= vr*(vc*dinv) is exact for row P (vr=d-1) and col P
// (wc[P]=1-dinv). Only the diagonal [P][P] is off by exactly +2, introduced
// once at step P and propagating additively (never re-read as pivot or
// broadcast) -> corrected once in the final write: out = -A + 2*[diag].
// det = prod pivots (>=1 since S >= I, Schur complements of S-I stay PSD).
// ---------------------------------------------------------------------------
__global__ __launch_bounds__(512) void k_sweep(const float* __restrict__ S,
    float* __restrict__ INVg, float* __restrict__ ld2) {
  const int c = blockIdx.x, t = threadIdx.x;
  __shared__ __align__(16) float vbuf[2][132];   // slot [128] carries d
  const float4* S4 = (const float4*)(S + c * 16384);
  float4 A[8];
  #pragma unroll
  for (int q = 0; q < 8; ++q) A[q] = S4[q * 512 + t];
  const int h = t >> 5, c4i = t & 31;
  float lda = 0.f;

  for (int P = 0; P < 128; ++P) {
    float* vb = vbuf[P & 1];
    // ---- export row P (32 threads: h == P&15), with in-LDS fixup ----
    if (h == (P & 15)) {
      const int qexp = P >> 4;
      float4 ex = A[0];
      #pragma unroll
      for (int q = 1; q < 8; ++q) if (q == qexp) ex = A[q];   // static-index select
      if (c4i == (P >> 2)) {                 // this float4 holds col P (diag d)
        const int e = P & 3;
        float dv = (e == 0) ? ex.x : (e == 1) ? ex.y : (e == 2) ? ex.z : ex.w;
        vb[128] = dv;                        // broadcast raw d
        if (e == 0) ex.x -= 1.f; else if (e == 1) ex.y -= 1.f;
        else if (e == 2) ex.z -= 1.f; else ex.w -= 1.f;       // vbuf[P] = d-1
      }
      ((float4*)vb)[c4i] = ex;
    }
    __syncthreads();
    // ---- generic rank-1 update, zero predication ----
    const float d = vb[128];
    const float dinv = 1.0f / d;
    lda += __log2f(d);
    const float4 vc = ((const float4*)vb)[c4i];
    const float4 wc = make_float4(vc.x * dinv, vc.y * dinv, vc.z * dinv, vc.w * dinv);
    #pragma unroll
    for (int q = 0; q < 8; ++q) {
      const float vr = vb[q * 16 + h];       // row-P lane reads d-1 automatically
      A[q].x -= vr * wc.x;
      A[q].y -= vr * wc.y;
      A[q].z -= vr * wc.z;
      A[q].w -= vr * wc.w;
    }
    // one barrier/step is safe: buf parity alternates; writes to buf[(P+2)&1]
    // are separated from step-P reads by step-(P+1)'s barrier.
  }

  // ---- write INV = -A, lazily fixing the +2 diag error ----
  float4* O4 = (float4*)(INVg + c * 16384);
  const int e = h & 3;                        // diag element position = rq & 3
  const float4 addv = make_float4(e == 0 ? 2.f : 0.f, e == 1 ? 2.f : 0.f,
                                  e == 2 ? 2.f : 0.f, e == 3 ? 2.f : 0.f);
  #pragma unroll
  for (int q = 0; q < 8; ++q) {
    const int rq = q * 16 + h;
    const float pf = (c4i == (rq >> 2)) ? 1.f : 0.f;
    float4 o;
    o.x = pf * addv.x - A[q].x;
    o.y = pf * addv.y - A[q].y;
    o.z = pf * addv.z - A[q].z;
    o.w = pf * addv.w - A[q].w;
    O4[q * 512 + t] = o;
  }
  if (t == 0) ld2[c] = lda;                   // v_log_f32 is log2 = slogdet/ln2
}

// ---------------------------------------------------------------------------
// K5: pairwise tr+quad fused: sum_f inv_j[f] * (S_i[f] + diff[a]*diff[b]);
// kl = 0.5*(ld2[j]-ld2[i] - 128 + sum); masked atomic accumulate.
// ---------------------------------------------------------------------------
__global__ __launch_bounds__(256) void k_pairs(const float* __restrict__ S,
    const float* __restrict__ INVg, const float* __restrict__ mu,
    const float* __restrict__ ld2, const int* __restrict__ rank_g,
    float* __restrict__ klacc) {
  const int j = blockIdx.x, i = blockIdx.y;
  if (rank_g[i] > C_CLS - 2 || rank_g[j] < 1) return;
  __shared__ __align__(16) float dl[128];
  __shared__ float wsum[4];
  const int t = threadIdx.x;
  if (t < 128) dl[t] = mu[i * 128 + t] - mu[j * 128 + t];
  __syncthreads();
  const float4* Si4 = (const float4*)(S + i * 16384);
  const float4* Ij4 = (const float4*)(INVg + j * 16384);
  float s = 0.f;
  #pragma unroll
  for (int q = 0; q < 16; ++q) {
    int f4 = q * 256 + t;
    int a = f4 >> 5, b4 = f4 & 31;
    float da = dl[a];
    float4 db = ((const float4*)dl)[b4];
    float4 si = Si4[f4], ij = Ij4[f4];
    s += ij.x * (si.x + da * db.x);
    s += ij.y * (si.y + da * db.y);
    s += ij.z * (si.z + da * db.z);
    s += ij.w * (si.w + da * db.w);
  }
  #pragma unroll
  for (int off = 32; off > 0; off >>= 1) s += __shfl_xor(s, off);
  if ((t & 63) == 0) wsum[t >> 6] = s;
  __syncthreads();
  if (t == 0) {
    float tot = wsum[0] + wsum[1] + wsum[2] + wsum[3];
    float kl = 0.5f * ((ld2[j] - ld2[i]) - 128.0f + tot);
    atomicAdd(klacc, kl);
  }
}

// ---------------------------------------------------------------------------
// K6: out = klacc - sum(mu^2)
// ---------------------------------------------------------------------------
__global__ __launch_bounds__(256) void k_final(const float* __restrict__ mu,
    const float* __restrict__ klacc, float* __restrict__ out) {
  const int t = threadIdx.x;
  __shared__ float wsum[4];
  float s = 0.f;
  #pragma unroll
  for (int q = 0; q < 16; ++q) {
    float m = mu[q * 256 + t];
    s += m * m;
  }
  #pragma unroll
  for (int off = 32; off > 0; off >>= 1) s += __shfl_xor(s, off);
  if ((t & 63) == 0) wsum[t >> 6] = s;
  __syncthreads();
  if (t == 0) out[0] = klacc[0] - (wsum[0] + wsum[1] + wsum[2] + wsum[3]);
}

extern "C" void kernel_launch(void* const* d_in, const int* in_sizes, int n_in,
                              void* d_out, int out_size, void* d_ws, size_t ws_size,
                              hipStream_t stream) {
  const float* feat  = (const float*)d_in[0];
  const int*   label = (const int*)d_in[1];
  // d_in[2] (pan) is unused by the reference module.
  float* out = (float*)d_out;
  char*  ws  = (char*)d_ws;

  int*   counts  = (int*)(ws + O_COUNTS);
  int*   rank_g  = (int*)(ws + O_RANK);
  int*   offs    = (int*)(ws + O_OFFS);
  float* klacc   = (float*)(ws + O_KLACC);
  float* ld2     = (float*)(ws + O_LD2);
  float* countsf = (float*)(ws + O_COUNTSF);
  float* colsum  = (float*)(ws + O_COLSUM);
  float* mu      = (float*)(ws + O_MU);
  int*   list    = (int*)(ws + O_LIST);
  float* S       = (float*)(ws + O_S);
  float* INVg    = (float*)(ws + O_INV);

  hipMemsetAsync(ws, 0, 18432, stream);                 // header + colsum
  hipMemsetAsync(S, 0, C_CLS * 16384 * 4, stream);      // M accumulators

  k_bucket  <<<1,            1024, 0, stream>>>(label, counts, rank_g, offs, countsf, list);
  k_scatter <<<128,           256, 0, stream>>>(feat, counts, offs, list, S, colsum);
  k_finalize<<<C_CLS,         256, 0, stream>>>(S, colsum, countsf, mu);
  k_sweep   <<<C_CLS,         512, 0, stream>>>(S, INVg, ld2);
  k_pairs   <<<dim3(C_CLS, C_CLS), 256, 0, stream>>>(S, INVg, mu, ld2, rank_g, klacc);
  k_final   <<<1,             256, 0, stream>>>(mu, klacc, out);
}

// Round 5
// 180.011 us; speedup vs baseline: 3.8339x; 1.2693x over previous
//
#include <hip/hip_runtime.h>

#define B_ROWS 16384
#define K_DIM  128
#define C_CLS  32

// ws layout (bytes)
#define O_COUNTS   0
#define O_FIRST    256
#define O_RANK     512
#define O_OFFS     768
#define O_KLACC    1024
#define O_LD2      1152
#define O_COUNTSF  1280
#define O_COLSUM   2048            // 32*128*4 = 16384
#define O_MU       18432           // 16384
#define O_LIST     34816           // 16384*4 = 65536
#define O_S        102400          // 32*16384*4 = 2 MiB
#define O_PART     (102400 + 2097152)      // 128 blocks * 64 KiB = 8 MiB
#define O_INV      O_PART          // aliased: partials die at k_finalize,
                                   // INV is produced by k_sweep afterwards

// ---------------------------------------------------------------------------
// K1: counts, first-occurrence, appearance rank, offsets, class bucket list.
// Single block so no grid sync needed. 1024 threads, 16 rows each.
// ---------------------------------------------------------------------------
__global__ __launch_bounds__(1024) void k_bucket(const int* __restrict__ label,
    int* __restrict__ counts, int* __restrict__ rank_g, int* __restrict__ offs,
    float* __restrict__ countsf, int* __restrict__ list) {
  __shared__ int lc[C_CLS], lf[C_CLS], loff[C_CLS], lcur[C_CLS];
  const int t = threadIdx.x;
  if (t < C_CLS) { lc[t] = 0; lf[t] = 0x7fffffff; lcur[t] = 0; }
  __syncthreads();
  #pragma unroll
  for (int q = 0; q < 16; ++q) {
    int i = q * 1024 + t;
    int c = label[i];
    atomicAdd(&lc[c], 1);
    atomicMin(&lf[c], i);
  }
  __syncthreads();
  if (t == 0) {
    int run = 0;
    for (int c = 0; c < C_CLS; ++c) { loff[c] = run; run += lc[c]; }
  }
  __syncthreads();
  if (t < C_CLS) {
    counts[t]  = lc[t];
    countsf[t] = (float)lc[t];
    offs[t]    = loff[t];
    // rank = stable double-argsort of first-occurrence
    int f = lf[t], r = 0;
    for (int c2 = 0; c2 < C_CLS; ++c2) {
      int f2 = lf[c2];
      r += (f2 < f) || (f2 == f && c2 < t);
    }
    rank_g[t] = r;
  }
  #pragma unroll
  for (int q = 0; q < 16; ++q) {
    int i = q * 1024 + t;
    int c = label[i];
    int pos = atomicAdd(&lcur[c], 1);
    list[loff[c] + pos] = i;
  }
}

// ---------------------------------------------------------------------------
// K2: per-class partial second moments. 4 splits per class -> 128 blocks.
// Each thread owns an 8x8 register tile of the 128x128 output.
// ATOMIC-FREE (r4 fix: 2M global atomicAdds were ~10 ops/cy device wall,
// 84 us, WRITE_SIZE 65 MB): each block writes its 64 KB partial to a
// private slab; k_finalize folds the 4 partials. colsum atomics kept
// (16K total, negligible).
// ---------------------------------------------------------------------------
__global__ __launch_bounds__(256) void k_scatter(const float* __restrict__ feat,
    const int* __restrict__ counts, const int* __restrict__ offs,
    const int* __restrict__ list, float* __restrict__ part, float* __restrict__ colsum) {
  const int c = blockIdx.x >> 2, s = blockIdx.x & 3;
  const int n = counts[c], off = offs[c];
  const int beg = off + (n * s) / 4, end = off + (n * (s + 1)) / 4;
  __shared__ __align__(16) float ls[32 * 128];
  const int t = threadIdx.x;
  const int tr = t >> 4, tc = t & 15;
  float acc[8][8];
  #pragma unroll
  for (int i = 0; i < 8; ++i)
    #pragma unroll
    for (int j = 0; j < 8; ++j) acc[i][j] = 0.f;
  float cs = 0.f;
  const int col = t & 127, half = t >> 7;
  for (int base = beg; base < end; base += 32) {
    const int nb = min(32, end - base);
    __syncthreads();             // protect ls against previous-iter readers
    #pragma unroll
    for (int w = 0; w < 4; ++w) {
      int f4 = w * 256 + t;      // 0..1023 over 32 rows x 32 float4
      int r = f4 >> 5, c4 = f4 & 31;
      float4 v = make_float4(0.f, 0.f, 0.f, 0.f);
      if (r < nb) {
        int row = list[base + r];
        v = ((const float4*)(feat + (long)row * K_DIM))[c4];
      }
      ((float4*)ls)[f4] = v;     // zero-padded tail rows contribute nothing
    }
    __syncthreads();
    #pragma unroll
    for (int r0 = 0; r0 < 16; ++r0) cs += ls[(half * 16 + r0) * 128 + col];
    for (int r = 0; r < nb; ++r) {
      const float4* lr = (const float4*)(ls + r * 128);
      float4 A0 = lr[tr * 2], A1 = lr[tr * 2 + 1];
      float4 B0 = lr[tc * 2], B1 = lr[tc * 2 + 1];
      float av[8] = {A0.x, A0.y, A0.z, A0.w, A1.x, A1.y, A1.z, A1.w};
      float bv[8] = {B0.x, B0.y, B0.z, B0.w, B1.x, B1.y, B1.z, B1.w};
      #pragma unroll
      for (int i = 0; i < 8; ++i)
        #pragma unroll
        for (int j = 0; j < 8; ++j) acc[i][j] += av[i] * bv[j];
    }
  }
  // non-atomic partial write, vectorized
  float* Pc = part + (long)blockIdx.x * 16384;
  #pragma unroll
  for (int i = 0; i < 8; ++i) {
    float4* prow = (float4*)(Pc + (tr * 8 + i) * 128);
    prow[tc * 2]     = make_float4(acc[i][0], acc[i][1], acc[i][2], acc[i][3]);
    prow[tc * 2 + 1] = make_float4(acc[i][4], acc[i][5], acc[i][6], acc[i][7]);
  }
  atomicAdd(&colsum[c * 128 + col], cs);
}

// ---------------------------------------------------------------------------
// K3: mu = colsum/n ; S = (sum of 4 partials)/n - mu mu^T + I
// ---------------------------------------------------------------------------
__global__ __launch_bounds__(256) void k_finalize(const float* __restrict__ part,
    float* __restrict__ S, const float* __restrict__ colsum,
    const float* __restrict__ countsf, float* __restrict__ mu) {
  const int c = blockIdx.x, t = threadIdx.x;
  __shared__ __align__(16) float ml[128];
  const float n = countsf[c];
  if (t < 128) {
    float m = colsum[c * 128 + t] / n;
    ml[t] = m;
    mu[c * 128 + t] = m;
  }
  __syncthreads();
  const float4* P0 = (const float4*)(part + (long)(c * 4 + 0) * 16384);
  const float4* P1 = (const float4*)(part + (long)(c * 4 + 1) * 16384);
  const float4* P2 = (const float4*)(part + (long)(c * 4 + 2) * 16384);
  const float4* P3 = (const float4*)(part + (long)(c * 4 + 3) * 16384);
  float4* S4 = (float4*)(S + c * 16384);
  const float rn = 1.0f / n;
  #pragma unroll
  for (int q = 0; q < 16; ++q) {
    int f4 = q * 256 + t;
    int a = f4 >> 5, b = (f4 & 31) * 4;
    float4 v0 = P0[f4], v1 = P1[f4], v2 = P2[f4], v3 = P3[f4];
    float4 v;
    v.x = (v0.x + v1.x) + (v2.x + v3.x);
    v.y = (v0.y + v1.y) + (v2.y + v3.y);
    v.z = (v0.z + v1.z) + (v2.z + v3.z);
    v.w = (v0.w + v1.w) + (v2.w + v3.w);
    float ma = ml[a];
    v.x = v.x * rn - ma * ml[b + 0] + ((a == b + 0) ? 1.f : 0.f);
    v.y = v.y * rn - ma * ml[b + 1] + ((a == b + 1) ? 1.f : 0.f);
    v.z = v.z * rn - ma * ml[b + 2] + ((a == b + 2) ? 1.f : 0.f);
    v.w = v.w * rn - ma * ml[b + 3] + ((a == b + 3) ? 1.f : 0.f);
    S4[f4] = v;
  }
}

// ---------------------------------------------------------------------------
// K4: sweep-operator inversion + log2-det. ROLLED loop (spill fix vs r2/r3:
// the 128-deep template unroll made A[]'s live ranges span 128 barriers ->
// LLVM greedy RA spilled ~11.6 KB/thread to scratch at ANY thread-state size;
// a rolled loop keeps the region small, all A[] indices remain static).
//
// Layout: 512 threads; thread t holds rows rq = 16q + h (h = t>>5, q=0..7),
// float4-cols [4*(t&31) .. +3] -> A[8] = 32 VGPRs of data.
//
// In-LDS pivot fixup removes ALL per-element predication from the hot loop:
// exporter writes row P with vbuf[P] := d-1 (and raw d into slot 128). Then
// the generic update A -= vr*(vc*dinv) is exact for row P (vr=d-1) and col P
// (wc[P]=1-dinv). Only the diagonal [P][P] is off by exactly +2, introduced
// once at step P and propagating additively (never re-read as pivot or
// broadcast) -> corrected once in the final write: out = -A + 2*[diag].
// det = prod pivots (>=1 since S >= I, Schur complements of S-I stay PSD).
// ---------------------------------------------------------------------------
__global__ __launch_bounds__(512) void k_sweep(const float* __restrict__ S,
    float* __restrict__ INVg, float* __restrict__ ld2) {
  const int c = blockIdx.x, t = threadIdx.x;
  __shared__ __align__(16) float vbuf[2][132];   // slot [128] carries d
  const float4* S4 = (const float4*)(S + c * 16384);
  float4 A[8];
  #pragma unroll
  for (int q = 0; q < 8; ++q) A[q] = S4[q * 512 + t];
  const int h = t >> 5, c4i = t & 31;
  float lda = 0.f;

  for (int P = 0; P < 128; ++P) {
    float* vb = vbuf[P & 1];
    // ---- export row P (32 threads: h == P&15), with in-LDS fixup ----
    if (h == (P & 15)) {
      const int qexp = P >> 4;
      float4 ex = A[0];
      #pragma unroll
      for (int q = 1; q < 8; ++q) if (q == qexp) ex = A[q];   // static-index select
      if (c4i == (P >> 2)) {                 // this float4 holds col P (diag d)
        const int e = P & 3;
        float dv = (e == 0) ? ex.x : (e == 1) ? ex.y : (e == 2) ? ex.z : ex.w;
        vb[128] = dv;                        // broadcast raw d
        if (e == 0) ex.x -= 1.f; else if (e == 1) ex.y -= 1.f;
        else if (e == 2) ex.z -= 1.f; else ex.w -= 1.f;       // vbuf[P] = d-1
      }
      ((float4*)vb)[c4i] = ex;
    }
    __syncthreads();
    // ---- generic rank-1 update, zero predication ----
    const float d = vb[128];
    const float dinv = 1.0f / d;
    lda += __log2f(d);
    const float4 vc = ((const float4*)vb)[c4i];
    const float4 wc = make_float4(vc.x * dinv, vc.y * dinv, vc.z * dinv, vc.w * dinv);
    #pragma unroll
    for (int q = 0; q < 8; ++q) {
      const float vr = vb[q * 16 + h];       // row-P lane reads d-1 automatically
      A[q].x -= vr * wc.x;
      A[q].y -= vr * wc.y;
      A[q].z -= vr * wc.z;
      A[q].w -= vr * wc.w;
    }
    // one barrier/step is safe: buf parity alternates; writes to buf[(P+2)&1]
    // are separated from step-P reads by step-(P+1)'s barrier.
  }

  // ---- write INV = -A, lazily fixing the +2 diag error ----
  float4* O4 = (float4*)(INVg + c * 16384);
  const int e = h & 3;                        // diag element position = rq & 3
  const float4 addv = make_float4(e == 0 ? 2.f : 0.f, e == 1 ? 2.f : 0.f,
                                  e == 2 ? 2.f : 0.f, e == 3 ? 2.f : 0.f);
  #pragma unroll
  for (int q = 0; q < 8; ++q) {
    const int rq = q * 16 + h;
    const float pf = (c4i == (rq >> 2)) ? 1.f : 0.f;
    float4 o;
    o.x = pf * addv.x - A[q].x;
    o.y = pf * addv.y - A[q].y;
    o.z = pf * addv.z - A[q].z;
    o.w = pf * addv.w - A[q].w;
    O4[q * 512 + t] = o;
  }
  if (t == 0) ld2[c] = lda;                   // v_log_f32 is log2 = slogdet/ln2
}

// ---------------------------------------------------------------------------
// K5: pairwise tr+quad fused: sum_f inv_j[f] * (S_i[f] + diff[a]*diff[b]);
// kl = 0.5*(ld2[j]-ld2[i] - 128 + sum); masked atomic accumulate.
// ---------------------------------------------------------------------------
__global__ __launch_bounds__(256) void k_pairs(const float* __restrict__ S,
    const float* __restrict__ INVg, const float* __restrict__ mu,
    const float* __restrict__ ld2, const int* __restrict__ rank_g,
    float* __restrict__ klacc) {
  const int j = blockIdx.x, i = blockIdx.y;
  if (rank_g[i] > C_CLS - 2 || rank_g[j] < 1) return;
  __shared__ __align__(16) float dl[128];
  __shared__ float wsum[4];
  const int t = threadIdx.x;
  if (t < 128) dl[t] = mu[i * 128 + t] - mu[j * 128 + t];
  __syncthreads();
  const float4* Si4 = (const float4*)(S + i * 16384);
  const float4* Ij4 = (const float4*)(INVg + j * 16384);
  float s = 0.f;
  #pragma unroll
  for (int q = 0; q < 16; ++q) {
    int f4 = q * 256 + t;
    int a = f4 >> 5, b4 = f4 & 31;
    float da = dl[a];
    float4 db = ((const float4*)dl)[b4];
    float4 si = Si4[f4], ij = Ij4[f4];
    s += ij.x * (si.x + da * db.x);
    s += ij.y * (si.y + da * db.y);
    s += ij.z * (si.z + da * db.z);
    s += ij.w * (si.w + da * db.w);
  }
  #pragma unroll
  for (int off = 32; off > 0; off >>= 1) s += __shfl_xor(s, off);
  if ((t & 63) == 0) wsum[t >> 6] = s;
  __syncthreads();
  if (t == 0) {
    float tot = wsum[0] + wsum[1] + wsum[2] + wsum[3];
    float kl = 0.5f * ((ld2[j] - ld2[i]) - 128.0f + tot);
    atomicAdd(klacc, kl);
  }
}

// ---------------------------------------------------------------------------
// K6: out = klacc - sum(mu^2)
// ---------------------------------------------------------------------------
__global__ __launch_bounds__(256) void k_final(const float* __restrict__ mu,
    const float* __restrict__ klacc, float* __restrict__ out) {
  const int t = threadIdx.x;
  __shared__ float wsum[4];
  float s = 0.f;
  #pragma unroll
  for (int q = 0; q < 16; ++q) {
    float m = mu[q * 256 + t];
    s += m * m;
  }
  #pragma unroll
  for (int off = 32; off > 0; off >>= 1) s += __shfl_xor(s, off);
  if ((t & 63) == 0) wsum[t >> 6] = s;
  __syncthreads();
  if (t == 0) out[0] = klacc[0] - (wsum[0] + wsum[1] + wsum[2] + wsum[3]);
}

extern "C" void kernel_launch(void* const* d_in, const int* in_sizes, int n_in,
                              void* d_out, int out_size, void* d_ws, size_t ws_size,
                              hipStream_t stream) {
  const float* feat  = (const float*)d_in[0];
  const int*   label = (const int*)d_in[1];
  // d_in[2] (pan) is unused by the reference module.
  float* out = (float*)d_out;
  char*  ws  = (char*)d_ws;

  int*   counts  = (int*)(ws + O_COUNTS);
  int*   rank_g  = (int*)(ws + O_RANK);
  int*   offs    = (int*)(ws + O_OFFS);
  float* klacc   = (float*)(ws + O_KLACC);
  float* ld2     = (float*)(ws + O_LD2);
  float* countsf = (float*)(ws + O_COUNTSF);
  float* colsum  = (float*)(ws + O_COLSUM);
  float* mu      = (float*)(ws + O_MU);
  int*   list    = (int*)(ws + O_LIST);
  float* S       = (float*)(ws + O_S);
  float* part    = (float*)(ws + O_PART);
  float* INVg    = (float*)(ws + O_INV);   // aliases part (sequenced after)

  hipMemsetAsync(ws, 0, 18432, stream);    // header + colsum (S no longer needs it)

  k_bucket  <<<1,            1024, 0, stream>>>(label, counts, rank_g, offs, countsf, list);
  k_scatter <<<128,           256, 0, stream>>>(feat, counts, offs, list, part, colsum);
  k_finalize<<<C_CLS,         256, 0, stream>>>(part, S, colsum, countsf, mu);
  k_sweep   <<<C_CLS,         512, 0, stream>>>(S, INVg, ld2);
  k_pairs   <<<dim3(C_CLS, C_CLS), 256, 0, stream>>>(S, INVg, mu, ld2, rank_g, klacc);
  k_final   <<<1,             256, 0, stream>>>(mu, klacc, out);
}